// Round 11
// baseline (212.449 us; speedup 1.0000x reference)
//
#include <hip/hip_runtime.h>

typedef unsigned short u16;
typedef __bf16 bf16x8 __attribute__((ext_vector_type(8)));
typedef float f32x4 __attribute__((ext_vector_type(4)));

// cheap float->bf16: round via +0x8000 then truncate (<=1ulp vs RNE)
__device__ __forceinline__ u16 f2bf_r(float f) {
    union { float f; unsigned u; } v; v.f = f;
    return (u16)((v.u + 0x8000u) >> 16);
}
__device__ __forceinline__ float rcpf(float x) { return __builtin_amdgcn_rcpf(x); }

__device__ __forceinline__ void gload_lds16(const u16* g, u16* l) {
    __builtin_amdgcn_global_load_lds(
        (const __attribute__((address_space(1))) void*)g,
        (__attribute__((address_space(3))) void*)l,
        16, 0, 0);
}

// ---------------------------------------------------------------------------
// Staging (r6-verified): per 64-row x 32-k group of 256 threads, thread t
// covers row t>>2, k-granule (t&3)^((t>>3)&3) -> 4 adjacent lanes = one
// aligned 64B line; LDS dest linear (t*8). Fragment read:
// (row&63)*32 + ((g^((fr>>1)&3))*8) -> 2-way bank alias (free).
// K-loop: 3 buffers, counted vmcnt (never 0 mid-loop), one barrier per K-step,
// stage(i+2) after the barrier. Proven race-free (r5/r6/r10, absmax-stable).
// ---------------------------------------------------------------------------

#define BM 128
#define BN 128
#define BK 32

template<int K, int RELU, int NBX>
__global__ __launch_bounds__(256) void gemm_bt(
    const u16* __restrict__ A, const u16* __restrict__ BT,
    const float* __restrict__ bias, u16* __restrict__ C,
    int M, int N)
{
    constexpr int NS = K / BK;
    __shared__ u16 smem[3 * 8192];
    const int t = threadIdx.x;
    const int lane = t & 63;
    const int wave = t >> 6;
    const int wr = (wave >> 1) * 64;
    const int wc = (wave & 1) * 64;

    const int nlin = blockIdx.x;
    const int jj = nlin >> 3;
    const long brow = (long)((nlin & 7) + 8 * (jj / NBX)) * BM;
    const long bcol = (long)(jj % NBX) * BN;

    const int sr = t >> 2;
    const int sc = ((t & 3) ^ ((t >> 3) & 3)) * 8;
    const u16* gA0 = A + (brow + sr) * (long)K + sc;
    const u16* gA1 = gA0 + 64L * K;
    const u16* gB0 = BT + (bcol + sr) * (long)K + sc;
    const u16* gB1 = gB0 + 64L * K;

    f32x4 acc[4][4] = {};
    const int fr = lane & 15;
    const int fbase = fr * 32 + (((lane >> 4) ^ ((fr >> 1) & 3)) * 8);

    auto STAGE = [&](int buf, int k0) {
        u16* As = &smem[buf * 8192];
        u16* Bs = As + 4096;
        gload_lds16(gA0 + k0, &As[t * 8]);
        gload_lds16(gA1 + k0, &As[2048 + t * 8]);
        gload_lds16(gB0 + k0, &Bs[t * 8]);
        gload_lds16(gB1 + k0, &Bs[2048 + t * 8]);
    };
    auto COMPUTE = [&](int buf) {
        const u16* As = &smem[buf * 8192];
        const u16* Bs = As + 4096;
        bf16x8 af[4], bfr[4];
#pragma unroll
        for (int m = 0; m < 4; ++m)
            af[m] = *(const bf16x8*)&As[wr * 32 + m * 512 + fbase];
#pragma unroll
        for (int n = 0; n < 4; ++n)
            bfr[n] = *(const bf16x8*)&Bs[wc * 32 + n * 512 + fbase];
        __builtin_amdgcn_s_setprio(1);
#pragma unroll
        for (int m = 0; m < 4; ++m)
#pragma unroll
            for (int n = 0; n < 4; ++n)
                acc[m][n] = __builtin_amdgcn_mfma_f32_16x16x32_bf16(
                    af[m], bfr[n], acc[m][n], 0, 0, 0);
        __builtin_amdgcn_s_setprio(0);
    };

    STAGE(0, 0);
    STAGE(1, BK);
#pragma unroll
    for (int i = 0; i < NS; ++i) {
        if (i < NS - 1) asm volatile("s_waitcnt vmcnt(4)" ::: "memory");
        else            asm volatile("s_waitcnt vmcnt(0)" ::: "memory");
        __builtin_amdgcn_s_barrier();
        __builtin_amdgcn_sched_barrier(0);
        if (i + 2 < NS) STAGE((i + 2) % 3, (i + 2) * BK);
        COMPUTE(i % 3);
    }

#pragma unroll
    for (int n = 0; n < 4; ++n) {
        const long col = bcol + wc + n * 16 + fr;
        const float bv = bias[col];
#pragma unroll
        for (int m = 0; m < 4; ++m) {
            const long row = brow + wr + m * 16 + (lane >> 4) * 4;
#pragma unroll
            for (int j = 0; j < 4; ++j) {
                float v = acc[m][n][j] + bv;
                if (RELU) v = fmaxf(v, 0.f);
                C[(row + j) * (long)N + col] = f2bf_r(v);
            }
        }
    }
}

// ---- fused GEMM3 (proven: 128x192 tile, 2x2 waves, 3-buf counted) + RQS ----
#define FBM 128
#define FBN 192
#define FBK 32
#define CLS 200   // padded LDS row stride (u16) for the C tile

template<int K>
__global__ __launch_bounds__(256) void gemm3_rqs(
    const u16* __restrict__ A,       // h2: B x K bf16
    const u16* __restrict__ BT,      // W2T padded: 1536 x K bf16
    const float* __restrict__ bias,  // b2p: 1536
    const float* __restrict__ x,     // B x 64 fp32
    float* __restrict__ z,           // B x 64 fp32
    float* __restrict__ ldp8)        // B x 8 fp32 partial logdet (per col-block)
{
    constexpr int NS = K / FBK;
    __shared__ u16 smem[3 * 10240];          // 60 KB; C-tile (25600 u16) aliases
    const int t = threadIdx.x;
    const int lane = t & 63;
    const int wave = t >> 6;
    const int wr = (wave >> 1) * 64;         // 2x2 wave grid: 64 rows x 96 cols
    const int wc = (wave & 1) * 96;

    const int nlin = blockIdx.x;             // 4096 blocks, NBX=8
    const int jj = nlin >> 3;
    const long brow = (long)((nlin & 7) + 8 * (jj >> 3)) * FBM;
    const int bx = jj & 7;
    const int bcol = bx * FBN;

    const int sr = t >> 2;
    const int sc = ((t & 3) ^ ((t >> 3) & 3)) * 8;
    const u16* gA0 = A + (brow + sr) * (long)K + sc;
    const u16* gB0 = BT + (long)(bcol + sr) * K + sc;

    f32x4 acc[4][6] = {};
    const int fr = lane & 15;
    const int gsel = ((lane >> 4) ^ ((fr >> 1) & 3)) * 8;
    const int fbase = fr * 32 + gsel;

    int b_off[6];
#pragma unroll
    for (int n = 0; n < 6; ++n) {
        int rb = wc + n * 16 + fr;
        b_off[n] = (rb >> 6) * 2048 + (rb & 63) * 32 + gsel;
    }

    auto STAGE = [&](int buf, int k0) {
        u16* As = &smem[buf * 10240];
        u16* Bs = As + 4096;
        gload_lds16(gA0 + k0,            &As[t * 8]);
        gload_lds16(gA0 + 64L * K + k0,  &As[2048 + t * 8]);
        gload_lds16(gB0 + k0,            &Bs[t * 8]);
        gload_lds16(gB0 + 64L * K + k0,  &Bs[2048 + t * 8]);
        gload_lds16(gB0 + 128L * K + k0, &Bs[4096 + t * 8]);
    };
    auto COMPUTE = [&](int buf) {
        const u16* As = &smem[buf * 10240];
        const u16* Bs = As + 4096;
        bf16x8 af[4], bfr[6];
#pragma unroll
        for (int m = 0; m < 4; ++m)
            af[m] = *(const bf16x8*)&As[wr * 32 + m * 512 + fbase];
#pragma unroll
        for (int n = 0; n < 6; ++n)
            bfr[n] = *(const bf16x8*)&Bs[b_off[n]];
        __builtin_amdgcn_s_setprio(1);
#pragma unroll
        for (int m = 0; m < 4; ++m)
#pragma unroll
            for (int n = 0; n < 6; ++n)
                acc[m][n] = __builtin_amdgcn_mfma_f32_16x16x32_bf16(
                    af[m], bfr[n], acc[m][n], 0, 0, 0);
        __builtin_amdgcn_s_setprio(0);
    };

    STAGE(0, 0);
    STAGE(1, FBK);
#pragma unroll
    for (int i = 0; i < NS; ++i) {
        if (i < NS - 1) asm volatile("s_waitcnt vmcnt(5)" ::: "memory");
        else            asm volatile("s_waitcnt vmcnt(0)" ::: "memory");
        __builtin_amdgcn_s_barrier();
        __builtin_amdgcn_sched_barrier(0);
        if (i + 2 < NS) STAGE((i + 2) % 3, (i + 2) * FBK);
        COMPUTE(i % 3);
    }
    __syncthreads();                          // before aliasing smem with C tile

    // C tile -> LDS as bf16 (+bias), padded rows (128 x 200 = 25600 u16)
#pragma unroll
    for (int n = 0; n < 6; ++n) {
        const int cl = wc + n * 16 + fr;
        const float bv = bias[bcol + cl];
#pragma unroll
        for (int m = 0; m < 4; ++m) {
            const int rl = wr + m * 16 + (lane >> 4) * 4;
#pragma unroll
            for (int j = 0; j < 4; ++j)
                smem[(rl + j) * CLS + cl] = f2bf_r(acc[m][n][j] + bv);
        }
    }
    __syncthreads();

    // RQS: 128 rows x 8 dims = 1024 (b,d) pairs; 4 per thread
    const int dbase = bx * 8;
#pragma unroll
    for (int pi = 0; pi < 4; ++pi) {
        const int p  = t + pi * 256;
        const int bl = p >> 3;
        const int dl = p & 7;
        const u16* pp = &smem[bl * CLS + dl * 24];
        bf16x8 v0 = *(const bf16x8*)(pp);        // widths
        bf16x8 v1 = *(const bf16x8*)(pp + 8);    // heights
        bf16x8 v2 = *(const bf16x8*)(pp + 16);   // raw derivs (7) + pad(=0)

        float w[8], h[8];
        float sw = 0.f, sh = 0.f;
#pragma unroll
        for (int i = 0; i < 8; ++i) { w[i] = __expf((float)v0[i]); sw += w[i]; }
#pragma unroll
        for (int i = 0; i < 8; ++i) { h[i] = __expf((float)v1[i]); sh += h[i]; }
        const float rw = 0.992f * rcpf(sw);
        const float rh = 0.992f * rcpf(sh);
#pragma unroll
        for (int i = 0; i < 8; ++i) w[i] = fmaf(w[i], rw, 0.001f);
#pragma unroll
        for (int i = 0; i < 8; ++i) h[i] = fmaf(h[i], rh, 0.001f);

        const long b = brow + bl;
        const int  d = dbase + dl;
        float xin = x[b * 64 + d];
        xin = fminf(fmaxf(xin, 0.f), 1.f);

        float x_k = 0.f, y_k = 0.f, w_k = w[0], h_k = h[0];
        float rk = 0.f, rk1 = (float)v2[0];
        bool isfirst = true, islast = false;
        float cw = 0.f, ch = 0.f;
#pragma unroll
        for (int i = 1; i < 8; ++i) {
            cw += w[i - 1]; ch += h[i - 1];
            if (cw < xin) {
                x_k = cw; y_k = ch; w_k = w[i]; h_k = h[i];
                rk = (float)v2[i - 1];
                rk1 = (i < 7) ? (float)v2[i] : 0.f;
                isfirst = false; islast = (i == 7);
            }
        }
        float sp_k  = __logf(1.f + __expf(rk));
        float sp_k1 = __logf(1.f + __expf(rk1));
        float d_k  = isfirst ? 1.f : sp_k  + 0.001f;
        float d_k1 = islast  ? 1.f : sp_k1 + 0.001f;

        const float inv_wk = rcpf(w_k);
        const float s   = h_k * inv_wk;
        const float th  = (xin - x_k) * inv_wk;
        const float omt = 1.f - th;
        const float t1t = th * omt;
        const float den = fmaf(d_k + d_k1 - 2.f * s, t1t, s);
        const float num = fmaf(s * th, th, d_k * t1t);
        const float out = fmaf(h_k * num, rcpf(den + 1e-6f), y_k);
        const float nom = s * s * fmaf(d_k1 * th, th, fmaf(2.f * s, t1t, d_k * omt * omt));
        const float logdet = __logf(nom) - __logf(fmaf(den, den, 1e-6f));

        z[b * 64 + d] = out;

        // partial log-det reduce over this block's 8 dims (dl == t&7)
        float r = logdet;
        r += __shfl_xor(r, 1, 64);
        r += __shfl_xor(r, 2, 64);
        r += __shfl_xor(r, 4, 64);
        if ((t & 7) == 0) ldp8[b * 8 + bx] = r;
    }
}

// final log-det: sum the 8 per-col-block partials per batch row
__global__ __launch_bounds__(256) void ld_reduce8(
    const float* __restrict__ ldp8, float* __restrict__ ld)
{
    const long b = (long)blockIdx.x * 256 + threadIdx.x;
    const f32x4 a = *(const f32x4*)&ldp8[b * 8];
    const f32x4 c = *(const f32x4*)&ldp8[b * 8 + 4];
    ld[b] = ((a[0] + a[1]) + (a[2] + a[3])) + ((c[0] + c[1]) + (c[2] + c[3]));
}

// ---------------------------------------------------------------------------
// prep_all: cvt_x (blocks 0..2047) + LDS-tiled COALESCED transposes:
//   W0T: 4 tiles (64k x 128n)   blocks 2048..2051
//   W1T: 16 tiles (128k x 128n) blocks 2052..2067
//   W2T: 48 tiles (128k x 128npad) blocks 2068..2115
//   bias pad: blocks 2116..2121
// LDS tile stored transposed [n][k] with ldk padded (+4) -> 2-way bank (free);
// re-read b64-aligned (k0 % 4 == 0). Both global sides fully coalesced.
// ---------------------------------------------------------------------------
__global__ __launch_bounds__(256) void prep_all(
    const float* __restrict__ x,  u16* __restrict__ xb,
    const float* __restrict__ W0, u16* __restrict__ W0T,
    const float* __restrict__ W1, u16* __restrict__ W1T,
    const float* __restrict__ W2, u16* __restrict__ W2T,
    const float* __restrict__ b2, float* __restrict__ b2p)
{
    __shared__ u16 lds[128 * 132];           // 33.8 KB (transpose tiles)
    const int bid = blockIdx.x;
    const int t = threadIdx.x;

    if (bid < 2048) {
        const long i8 = ((long)bid * 256 + t) * 8;
        const f32x4 v0 = *(const f32x4*)&x[i8];
        const f32x4 v1 = *(const f32x4*)&x[i8 + 4];
        u16 o[8];
#pragma unroll
        for (int j = 0; j < 4; ++j) o[j] = f2bf_r(v0[j]);
#pragma unroll
        for (int j = 0; j < 4; ++j) o[4 + j] = f2bf_r(v1[j]);
        *(ulong2*)&xb[i8] = *(const ulong2*)o;
    } else if (bid < 2052) {
        // W0T tile: 64k x 128n, n0 = tile*128. src W0[k*512 + n] (coalesced in n)
        const int n0 = (bid - 2048) * 128;
#pragma unroll
        for (int rr = 0; rr < 32; ++rr) {
            const int idx = rr * 256 + t;          // 8192 elems
            const int nl = idx & 127, k = idx >> 7; // k in [0,64)
            lds[nl * 68 + k] = f2bf_r(W0[k * 512 + n0 + nl]);
        }
        __syncthreads();
        // write: thread t -> n_local = t>>1, k0 = (t&1)*32; 32 consec k
        const int nl = t >> 1, k0 = (t & 1) * 32;
#pragma unroll
        for (int j = 0; j < 8; ++j) {
            ulong v = *(const ulong*)&lds[nl * 68 + k0 + j * 4];
            *(ulong*)&W0T[(long)(n0 + nl) * 64 + k0 + j * 4] = v;
        }
    } else if (bid < 2068) {
        // W1T tile: 128k x 128n. tile = (bid-2052): kt = tile>>2, nt = tile&3
        const int tile = bid - 2052;
        const int k0t = (tile >> 2) * 128, n0 = (tile & 3) * 128;
#pragma unroll
        for (int rr = 0; rr < 64; ++rr) {
            const int idx = rr * 256 + t;          // 16384 elems
            const int nl = idx & 127, k = idx >> 7; // k in [0,128)
            lds[nl * 132 + k] = f2bf_r(W1[(long)(k0t + k) * 512 + n0 + nl]);
        }
        __syncthreads();
        // write: thread t -> nl = t>>1, k0 = (t&1)*64; 64 consec k
        const int nl = t >> 1, k0 = (t & 1) * 64;
#pragma unroll
        for (int j = 0; j < 16; ++j) {
            ulong v = *(const ulong*)&lds[nl * 132 + k0 + j * 4];
            *(ulong*)&W1T[(long)(n0 + nl) * 512 + k0t + k0 + j * 4] = v;
        }
    } else if (bid < 2116) {
        // W2T tile: 128k x 128npad. tile = (bid-2068): kt = tile/12, nt = tile%12
        const int tile = bid - 2068;
        const int k0t = (tile / 12) * 128, n0 = (tile % 12) * 128;
#pragma unroll
        for (int rr = 0; rr < 64; ++rr) {
            const int idx = rr * 256 + t;
            const int nl = idx & 127, k = idx >> 7;
            const int npad = n0 + nl;
            const int g = npad / 24, r = npad % 24;
            float v = (r < 23) ? W2[(long)(k0t + k) * 1472 + g * 23 + r] : 0.f;
            lds[nl * 132 + k] = f2bf_r(v);
        }
        __syncthreads();
        const int nl = t >> 1, k0 = (t & 1) * 64;
#pragma unroll
        for (int j = 0; j < 16; ++j) {
            ulong v = *(const ulong*)&lds[nl * 132 + k0 + j * 4];
            *(ulong*)&W2T[(long)(n0 + nl) * 512 + k0t + k0 + j * 4] = v;
        }
    } else {
        const int c = (bid - 2116) * 256 + t;
        if (c < 1536) {
            const int g = c / 24, r = c % 24;
            b2p[c] = (r < 23) ? b2[g * 23 + r] : 0.f;
        }
    }
}

__global__ void fill_fail(float* __restrict__ out, long n) {
    long i = (long)blockIdx.x * blockDim.x + threadIdx.x;
    long stride = (long)gridDim.x * blockDim.x;
    for (; i < n; i += stride) out[i] = -1.0f;
}

extern "C" void kernel_launch(void* const* d_in, const int* in_sizes, int n_in,
                              void* d_out, int out_size, void* d_ws, size_t ws_size,
                              hipStream_t stream)
{
    const float* x  = (const float*)d_in[0];
    const float* W0 = (const float*)d_in[1];
    const float* b0 = (const float*)d_in[2];
    const float* W1 = (const float*)d_in[3];
    const float* b1 = (const float*)d_in[4];
    const float* W2 = (const float*)d_in[5];
    const float* b2 = (const float*)d_in[6];
    const int B = in_sizes[0] / 64;   // 65536
    const int D = 64, H = 512, NP = 1536;

    char* ws = (char*)d_ws;
    size_t off = 0;
    u16* W0T = (u16*)(ws + off); off += (size_t)H * D * 2;
    u16* W1T = (u16*)(ws + off); off += (size_t)H * H * 2;
    u16* W2T = (u16*)(ws + off); off += (size_t)NP * H * 2;
    float* b2p = (float*)(ws + off); off += (size_t)NP * 4;
    off = (off + 255) & ~(size_t)255;
    // regionA: h1 during GEMM1/2, then ldp8 (f32 B*8) during fused+reduce
    u16*   h1   = (u16*)(ws + off);
    float* ldp8 = (float*)(ws + off);
    off += (size_t)B * H * 2;
    // regionB: xb during GEMM1 (dead after), then h2
    u16* xb = (u16*)(ws + off);
    u16* h2 = (u16*)(ws + off);
    off += (size_t)B * H * 2;
    size_t need = off;

    float* zout  = (float*)d_out;
    float* ldout = zout + (size_t)B * D;

    if (ws_size < need) {
        fill_fail<<<2048, 256, 0, stream>>>(zout, (long)out_size);
        return;
    }

    prep_all<<<2122, 256, 0, stream>>>(x, xb, W0, W0T, W1, W1T, W2, W2T, b2, b2p);

    gemm_bt<64, 1, 4><<<2048, 256, 0, stream>>>(xb, W0T, b0, h1, B, H);
    gemm_bt<512, 1, 4><<<2048, 256, 0, stream>>>(h1, W1T, b1, h2, B, H);

    // 128x192 tiles: 512 row-blocks x 8 col-blocks (proven geometry)
    gemm3_rqs<512><<<4096, 256, 0, stream>>>(h2, W2T, b2p, x, zout, ldp8);

    ld_reduce8<<<B / 256, 256, 0, stream>>>(ldp8, ldout);
}

// Round 12
// 197.492 us; speedup vs baseline: 1.0757x; 1.0757x over previous
//
#include <hip/hip_runtime.h>

typedef unsigned short u16;
typedef __bf16 bf16x8 __attribute__((ext_vector_type(8)));
typedef float f32x4 __attribute__((ext_vector_type(4)));

// cheap float->bf16: round via +0x8000 then truncate (<=1ulp vs RNE)
__device__ __forceinline__ u16 f2bf_r(float f) {
    union { float f; unsigned u; } v; v.f = f;
    return (u16)((v.u + 0x8000u) >> 16);
}
__device__ __forceinline__ float rcpf(float x) { return __builtin_amdgcn_rcpf(x); }

__device__ __forceinline__ void gload_lds16(const u16* g, u16* l) {
    __builtin_amdgcn_global_load_lds(
        (const __attribute__((address_space(1))) void*)g,
        (__attribute__((address_space(3))) void*)l,
        16, 0, 0);
}

// ---------------------------------------------------------------------------
// Staging (r6-verified): per 64-row x 32-k group of 256 threads, thread t
// covers row t>>2, k-granule (t&3)^((t>>3)&3) -> 4 adjacent lanes = one
// aligned 64B line; LDS dest linear (t*8). Fragment read:
// (row&63)*32 + ((g^((fr>>1)&3))*8) -> 2-way bank alias (free).
// K-loop: 3 buffers, counted vmcnt (never 0 mid-loop), one barrier per K-step,
// stage(i+2) after the barrier. Proven race-free (r5/r6/r10, absmax-stable).
// ---------------------------------------------------------------------------

#define BM 128
#define BN 128
#define BK 32

template<int K, int RELU, int NBX>
__global__ __launch_bounds__(256) void gemm_bt(
    const u16* __restrict__ A, const u16* __restrict__ BT,
    const float* __restrict__ bias, u16* __restrict__ C,
    int M, int N)
{
    constexpr int NS = K / BK;
    __shared__ u16 smem[3 * 8192];
    const int t = threadIdx.x;
    const int lane = t & 63;
    const int wave = t >> 6;
    const int wr = (wave >> 1) * 64;
    const int wc = (wave & 1) * 64;

    const int nlin = blockIdx.x;
    const int jj = nlin >> 3;
    const long brow = (long)((nlin & 7) + 8 * (jj / NBX)) * BM;
    const long bcol = (long)(jj % NBX) * BN;

    const int sr = t >> 2;
    const int sc = ((t & 3) ^ ((t >> 3) & 3)) * 8;
    const u16* gA0 = A + (brow + sr) * (long)K + sc;
    const u16* gA1 = gA0 + 64L * K;
    const u16* gB0 = BT + (bcol + sr) * (long)K + sc;
    const u16* gB1 = gB0 + 64L * K;

    f32x4 acc[4][4] = {};
    const int fr = lane & 15;
    const int fbase = fr * 32 + (((lane >> 4) ^ ((fr >> 1) & 3)) * 8);

    auto STAGE = [&](int buf, int k0) {
        u16* As = &smem[buf * 8192];
        u16* Bs = As + 4096;
        gload_lds16(gA0 + k0, &As[t * 8]);
        gload_lds16(gA1 + k0, &As[2048 + t * 8]);
        gload_lds16(gB0 + k0, &Bs[t * 8]);
        gload_lds16(gB1 + k0, &Bs[2048 + t * 8]);
    };
    auto COMPUTE = [&](int buf) {
        const u16* As = &smem[buf * 8192];
        const u16* Bs = As + 4096;
        bf16x8 af[4], bfr[4];
#pragma unroll
        for (int m = 0; m < 4; ++m)
            af[m] = *(const bf16x8*)&As[wr * 32 + m * 512 + fbase];
#pragma unroll
        for (int n = 0; n < 4; ++n)
            bfr[n] = *(const bf16x8*)&Bs[wc * 32 + n * 512 + fbase];
#pragma unroll
        for (int m = 0; m < 4; ++m)
#pragma unroll
            for (int n = 0; n < 4; ++n)
                acc[m][n] = __builtin_amdgcn_mfma_f32_16x16x32_bf16(
                    af[m], bfr[n], acc[m][n], 0, 0, 0);
    };

    STAGE(0, 0);
    STAGE(1, BK);
#pragma unroll
    for (int i = 0; i < NS; ++i) {
        if (i < NS - 1) asm volatile("s_waitcnt vmcnt(4)" ::: "memory");
        else            asm volatile("s_waitcnt vmcnt(0)" ::: "memory");
        __builtin_amdgcn_s_barrier();
        __builtin_amdgcn_sched_barrier(0);
        if (i + 2 < NS) STAGE((i + 2) % 3, (i + 2) * BK);
        COMPUTE(i % 3);
    }

#pragma unroll
    for (int n = 0; n < 4; ++n) {
        const long col = bcol + wc + n * 16 + fr;
        const float bv = bias[col];
#pragma unroll
        for (int m = 0; m < 4; ++m) {
            const long row = brow + wr + m * 16 + (lane >> 4) * 4;
#pragma unroll
            for (int j = 0; j < 4; ++j) {
                float v = acc[m][n][j] + bv;
                if (RELU) v = fmaxf(v, 0.f);
                C[(row + j) * (long)N + col] = f2bf_r(v);
            }
        }
    }
}

// ---- fused GEMM3 (proven: 128x192 tile, 2x2 waves, 3-buf counted) + RQS ----
#define FBM 128
#define FBN 192
#define FBK 32
#define CLS 200   // padded LDS row stride (u16) for the C tile

template<int K>
__global__ __launch_bounds__(256) void gemm3_rqs(
    const u16* __restrict__ A,       // h2: B x K bf16
    const u16* __restrict__ BT,      // W2T padded: 1536 x K bf16
    const float* __restrict__ bias,  // b2p: 1536
    const float* __restrict__ x,     // B x 64 fp32
    float* __restrict__ z,           // B x 64 fp32
    float* __restrict__ ldp8)        // B x 8 fp32 partial logdet (per col-block)
{
    constexpr int NS = K / FBK;
    __shared__ u16 smem[3 * 10240];          // 60 KB; C-tile (25600 u16) aliases
    const int t = threadIdx.x;
    const int lane = t & 63;
    const int wave = t >> 6;
    const int wr = (wave >> 1) * 64;         // 2x2 wave grid: 64 rows x 96 cols
    const int wc = (wave & 1) * 96;

    const int nlin = blockIdx.x;             // 4096 blocks, NBX=8
    const int jj = nlin >> 3;
    const long brow = (long)((nlin & 7) + 8 * (jj >> 3)) * FBM;
    const int bx = jj & 7;
    const int bcol = bx * FBN;

    const int sr = t >> 2;
    const int sc = ((t & 3) ^ ((t >> 3) & 3)) * 8;
    const u16* gA0 = A + (brow + sr) * (long)K + sc;
    const u16* gB0 = BT + (long)(bcol + sr) * K + sc;

    f32x4 acc[4][6] = {};
    const int fr = lane & 15;
    const int gsel = ((lane >> 4) ^ ((fr >> 1) & 3)) * 8;
    const int fbase = fr * 32 + gsel;

    int b_off[6];
#pragma unroll
    for (int n = 0; n < 6; ++n) {
        int rb = wc + n * 16 + fr;
        b_off[n] = (rb >> 6) * 2048 + (rb & 63) * 32 + gsel;
    }

    auto STAGE = [&](int buf, int k0) {
        u16* As = &smem[buf * 10240];
        u16* Bs = As + 4096;
        gload_lds16(gA0 + k0,            &As[t * 8]);
        gload_lds16(gA0 + 64L * K + k0,  &As[2048 + t * 8]);
        gload_lds16(gB0 + k0,            &Bs[t * 8]);
        gload_lds16(gB0 + 64L * K + k0,  &Bs[2048 + t * 8]);
        gload_lds16(gB0 + 128L * K + k0, &Bs[4096 + t * 8]);
    };
    auto COMPUTE = [&](int buf) {
        const u16* As = &smem[buf * 10240];
        const u16* Bs = As + 4096;
        bf16x8 af[4], bfr[6];
#pragma unroll
        for (int m = 0; m < 4; ++m)
            af[m] = *(const bf16x8*)&As[wr * 32 + m * 512 + fbase];
#pragma unroll
        for (int n = 0; n < 6; ++n)
            bfr[n] = *(const bf16x8*)&Bs[b_off[n]];
#pragma unroll
        for (int m = 0; m < 4; ++m)
#pragma unroll
            for (int n = 0; n < 6; ++n)
                acc[m][n] = __builtin_amdgcn_mfma_f32_16x16x32_bf16(
                    af[m], bfr[n], acc[m][n], 0, 0, 0);
    };

    STAGE(0, 0);
    STAGE(1, FBK);
#pragma unroll
    for (int i = 0; i < NS; ++i) {
        if (i < NS - 1) asm volatile("s_waitcnt vmcnt(5)" ::: "memory");
        else            asm volatile("s_waitcnt vmcnt(0)" ::: "memory");
        __builtin_amdgcn_s_barrier();
        __builtin_amdgcn_sched_barrier(0);
        if (i + 2 < NS) STAGE((i + 2) % 3, (i + 2) * FBK);
        COMPUTE(i % 3);
    }
    __syncthreads();                          // before aliasing smem with C tile

    // C tile -> LDS as bf16 (+bias), padded rows (128 x 200 = 25600 u16)
#pragma unroll
    for (int n = 0; n < 6; ++n) {
        const int cl = wc + n * 16 + fr;
        const float bv = bias[bcol + cl];
#pragma unroll
        for (int m = 0; m < 4; ++m) {
            const int rl = wr + m * 16 + (lane >> 4) * 4;
#pragma unroll
            for (int j = 0; j < 4; ++j)
                smem[(rl + j) * CLS + cl] = f2bf_r(acc[m][n][j] + bv);
        }
    }
    __syncthreads();

    // RQS: 128 rows x 8 dims = 1024 (b,d) pairs; 4 per thread
    const int dbase = bx * 8;
#pragma unroll
    for (int pi = 0; pi < 4; ++pi) {
        const int p  = t + pi * 256;
        const int bl = p >> 3;
        const int dl = p & 7;
        const u16* pp = &smem[bl * CLS + dl * 24];
        bf16x8 v0 = *(const bf16x8*)(pp);        // widths
        bf16x8 v1 = *(const bf16x8*)(pp + 8);    // heights
        bf16x8 v2 = *(const bf16x8*)(pp + 16);   // raw derivs (7) + pad(=0)

        float w[8], h[8];
        float sw = 0.f, sh = 0.f;
#pragma unroll
        for (int i = 0; i < 8; ++i) { w[i] = __expf((float)v0[i]); sw += w[i]; }
#pragma unroll
        for (int i = 0; i < 8; ++i) { h[i] = __expf((float)v1[i]); sh += h[i]; }
        const float rw = 0.992f * rcpf(sw);
        const float rh = 0.992f * rcpf(sh);
#pragma unroll
        for (int i = 0; i < 8; ++i) w[i] = fmaf(w[i], rw, 0.001f);
#pragma unroll
        for (int i = 0; i < 8; ++i) h[i] = fmaf(h[i], rh, 0.001f);

        const long b = brow + bl;
        const int  d = dbase + dl;
        float xin = x[b * 64 + d];
        xin = fminf(fmaxf(xin, 0.f), 1.f);

        float x_k = 0.f, y_k = 0.f, w_k = w[0], h_k = h[0];
        float rk = 0.f, rk1 = (float)v2[0];
        bool isfirst = true, islast = false;
        float cw = 0.f, ch = 0.f;
#pragma unroll
        for (int i = 1; i < 8; ++i) {
            cw += w[i - 1]; ch += h[i - 1];
            if (cw < xin) {
                x_k = cw; y_k = ch; w_k = w[i]; h_k = h[i];
                rk = (float)v2[i - 1];
                rk1 = (i < 7) ? (float)v2[i] : 0.f;
                isfirst = false; islast = (i == 7);
            }
        }
        float sp_k  = __logf(1.f + __expf(rk));
        float sp_k1 = __logf(1.f + __expf(rk1));
        float d_k  = isfirst ? 1.f : sp_k  + 0.001f;
        float d_k1 = islast  ? 1.f : sp_k1 + 0.001f;

        const float inv_wk = rcpf(w_k);
        const float s   = h_k * inv_wk;
        const float th  = (xin - x_k) * inv_wk;
        const float omt = 1.f - th;
        const float t1t = th * omt;
        const float den = fmaf(d_k + d_k1 - 2.f * s, t1t, s);
        const float num = fmaf(s * th, th, d_k * t1t);
        const float out = fmaf(h_k * num, rcpf(den + 1e-6f), y_k);
        const float nom = s * s * fmaf(d_k1 * th, th, fmaf(2.f * s, t1t, d_k * omt * omt));
        const float logdet = __logf(nom) - __logf(fmaf(den, den, 1e-6f));

        z[b * 64 + d] = out;

        // partial log-det reduce over this block's 8 dims (dl == t&7)
        float r = logdet;
        r += __shfl_xor(r, 1, 64);
        r += __shfl_xor(r, 2, 64);
        r += __shfl_xor(r, 4, 64);
        if ((t & 7) == 0) ldp8[b * 8 + bx] = r;
    }
}

// final log-det: sum the 8 per-col-block partials per batch row
__global__ __launch_bounds__(256) void ld_reduce8(
    const float* __restrict__ ldp8, float* __restrict__ ld)
{
    const long b = (long)blockIdx.x * 256 + threadIdx.x;
    const f32x4 a = *(const f32x4*)&ldp8[b * 8];
    const f32x4 c = *(const f32x4*)&ldp8[b * 8 + 4];
    ld[b] = ((a[0] + a[1]) + (a[2] + a[3])) + ((c[0] + c[1]) + (c[2] + c[3]));
}

// One fused prep kernel: cvt_x (blocks 0-2047), W0T (2048-2175),
// W1T (2176-3199), W2T (3200-6271), pad_bias2 (6272-6277).
// Scattered transpose reads are L2-absorbed (W0/W1/W2 <= 3MB, L2-resident);
// r11's LDS-tiled version was tail-latency-bound and SLOWER. Keep this form.
__global__ __launch_bounds__(256) void prep_all(
    const float* __restrict__ x,  u16* __restrict__ xb,
    const float* __restrict__ W0, u16* __restrict__ W0T,
    const float* __restrict__ W1, u16* __restrict__ W1T,
    const float* __restrict__ W2, u16* __restrict__ W2T,
    const float* __restrict__ b2, float* __restrict__ b2p)
{
    const int bid = blockIdx.x;
    const int t = threadIdx.x;
    if (bid < 2048) {
        const long i8 = ((long)bid * 256 + t) * 8;
        const f32x4 v0 = *(const f32x4*)&x[i8];
        const f32x4 v1 = *(const f32x4*)&x[i8 + 4];
        u16 o[8];
#pragma unroll
        for (int j = 0; j < 4; ++j) o[j] = f2bf_r(v0[j]);
#pragma unroll
        for (int j = 0; j < 4; ++j) o[4 + j] = f2bf_r(v1[j]);
        *(ulong2*)&xb[i8] = *(const ulong2*)o;
    } else if (bid < 2176) {
        const int i = (bid - 2048) * 256 + t;
        const int n = i >> 6, k = i & 63;
        W0T[i] = f2bf_r(W0[k * 512 + n]);
    } else if (bid < 3200) {
        const int i = (bid - 2176) * 256 + t;
        const int n = i >> 9, k = i & 511;
        W1T[i] = f2bf_r(W1[k * 512 + n]);
    } else if (bid < 6272) {
        const int i = (bid - 3200) * 256 + t;
        const int npad = i >> 9, k = i & 511;
        const int g = npad / 24, r = npad % 24;
        float v = (r < 23) ? W2[(long)k * 1472 + g * 23 + r] : 0.f;
        W2T[i] = f2bf_r(v);
    } else {
        const int c = (bid - 6272) * 256 + t;
        if (c < 1536) {
            const int g = c / 24, r = c % 24;
            b2p[c] = (r < 23) ? b2[g * 23 + r] : 0.f;
        }
    }
}

__global__ void fill_fail(float* __restrict__ out, long n) {
    long i = (long)blockIdx.x * blockDim.x + threadIdx.x;
    long stride = (long)gridDim.x * blockDim.x;
    for (; i < n; i += stride) out[i] = -1.0f;
}

extern "C" void kernel_launch(void* const* d_in, const int* in_sizes, int n_in,
                              void* d_out, int out_size, void* d_ws, size_t ws_size,
                              hipStream_t stream)
{
    const float* x  = (const float*)d_in[0];
    const float* W0 = (const float*)d_in[1];
    const float* b0 = (const float*)d_in[2];
    const float* W1 = (const float*)d_in[3];
    const float* b1 = (const float*)d_in[4];
    const float* W2 = (const float*)d_in[5];
    const float* b2 = (const float*)d_in[6];
    const int B = in_sizes[0] / 64;   // 65536
    const int D = 64, H = 512, NP = 1536;

    char* ws = (char*)d_ws;
    size_t off = 0;
    u16* W0T = (u16*)(ws + off); off += (size_t)H * D * 2;
    u16* W1T = (u16*)(ws + off); off += (size_t)H * H * 2;
    u16* W2T = (u16*)(ws + off); off += (size_t)NP * H * 2;
    float* b2p = (float*)(ws + off); off += (size_t)NP * 4;
    off = (off + 255) & ~(size_t)255;
    // regionA: h1 during GEMM1/2, then ldp8 (f32 B*8) during fused+reduce
    u16*   h1   = (u16*)(ws + off);
    float* ldp8 = (float*)(ws + off);
    off += (size_t)B * H * 2;
    // regionB: xb during GEMM1 (dead after), then h2
    u16* xb = (u16*)(ws + off);
    u16* h2 = (u16*)(ws + off);
    off += (size_t)B * H * 2;
    size_t need = off;

    float* zout  = (float*)d_out;
    float* ldout = zout + (size_t)B * D;

    if (ws_size < need) {
        fill_fail<<<2048, 256, 0, stream>>>(zout, (long)out_size);
        return;
    }

    prep_all<<<6278, 256, 0, stream>>>(x, xb, W0, W0T, W1, W1T, W2, W2T, b2, b2p);

    gemm_bt<64, 1, 4><<<2048, 256, 0, stream>>>(xb, W0T, b0, h1, B, H);
    gemm_bt<512, 1, 4><<<2048, 256, 0, stream>>>(h1, W1T, b1, h2, B, H);

    // 128x192 tiles: 512 row-blocks x 8 col-blocks (proven geometry)
    gemm3_rqs<512><<<4096, 256, 0, stream>>>(h2, W2T, b2p, x, zout, ldp8);

    ld_reduce8<<<B / 256, 256, 0, stream>>>(ldp8, ldout);
}